// Round 7
// baseline (1293.923 us; speedup 1.0000x reference)
//
#include <hip/hip_runtime.h>
#include <hip/hip_bf16.h>
#include <cmath>

#define TBL (1 << 19)   // T = 2^19 hash table entries per level (power of two)

__device__ __forceinline__ float relu_f(float x) { return fmaxf(x, 0.0f); }

// fp32 -> bf16 bits, round-to-nearest-even
__device__ __forceinline__ unsigned short f2bf(float x) {
    union { float f; unsigned u; } v; v.f = x;
    const unsigned r = v.u + 0x7FFFu + ((v.u >> 16) & 1u);
    return (unsigned short)(r >> 16);
}

typedef __attribute__((ext_vector_type(8))) short short8;   // 8 bf16 = 4 VGPRs (A/B frag)
typedef __attribute__((ext_vector_type(4))) float floatx4;  // C/D frag

// res_l = floor(16 * 1.3819^l); dense iff (res+1)^3 <= 2^19  (l = 0..4)
#define RES_LIST {16, 22, 30, 42, 58, 80, 111, 153, 212, 294, 406, 561, 775, 1072, 1481, 2047}

// ---------------------------------------------------------------------------
// XCD-pinned encode, v3: corner-PAIR loads.
// For each (cy,cz) pair the two x-corners are idx_a (x0) and idx_b (x0+1).
//  hashed: idx_b == idx_a^1 when x0 even;  dense: idx_b == idx_a+1 == idx_a^1
//  when idx_a even. Either way the 16 B-aligned block {idx&~1, idx|1} covers
//  both corners for ~half the lanes. Always load that block (one dwordx4,
//  16 B aligned), plus a predicated float2 gather for lanes whose idx_b is
//  not the buddy. Gather lane-slots per level: 8x64 -> 4x64 + 4x~32 (-25%).
// Theory test: encode is TA-request-rate bound (per-lane); if per-unique-line
// instead, this is neutral.
// ---------------------------------------------------------------------------
__global__ __launch_bounds__(256, 8)
void encode_pinned(const float* __restrict__ xyz,
                   const float* __restrict__ table,
                   float* __restrict__ ws_enc,      // float2 slots [level*n + i]
                   unsigned levels_packed,
                   int n)
{
    constexpr unsigned RES[16] = RES_LIST;

    const unsigned sub = blockIdx.x & 7u;
    const unsigned level = (levels_packed >> (4u * sub)) & 0xFu;
    const int i = (int)(blockIdx.x >> 3) * 256 + (int)threadIdx.x;
    if (i >= n) return;

    const float px_ = __builtin_nontemporal_load(xyz + 3 * (size_t)i + 0);
    const float py_ = __builtin_nontemporal_load(xyz + 3 * (size_t)i + 1);
    const float pz_ = __builtin_nontemporal_load(xyz + 3 * (size_t)i + 2);

    const unsigned res = RES[level];
    const float fr = (float)res;
    const float posx = px_ * fr, posy = py_ * fr, posz = pz_ * fr;
    const float fx = floorf(posx), fy = floorf(posy), fz = floorf(posz);
    const float wx = posx - fx, wy = posy - fy, wz = posz - fz;
    const unsigned x0 = (unsigned)fx, y0 = (unsigned)fy, z0 = (unsigned)fz;
    const float* tb = table + (size_t)level * (TBL * 2);
    const bool dense = (level < 5);      // wave-uniform
    const unsigned s = res + 1u;
    const unsigned s2 = s * s;

    float a0 = 0.0f, a1 = 0.0f;
#pragma unroll
    for (int p = 0; p < 4; ++p) {
        const unsigned cy = y0 + (p & 1);
        const unsigned cz = z0 + (p >> 1);
        unsigned ia, ib;
        if (dense) {
            ia = x0 + cy * s + cz * s2;
            ib = ia + 1u;
        } else {
            const unsigned h = (cy * 2654435761u) ^ (cz * 805459861u);
            ia = (x0 ^ h) & (unsigned)(TBL - 1);
            ib = ((x0 + 1u) ^ h) & (unsigned)(TBL - 1);
        }
        const float wyz = ((p & 1) ? wy : 1.0f - wy) * ((p & 2) ? wz : 1.0f - wz);
        const float wa = (1.0f - wx) * wyz;
        const float wb = wx * wyz;

        // 16 B-aligned block holding entries {ia&~1, ia|1}
        const float4 blk = *reinterpret_cast<const float4*>(tb + 2u * (ia & ~1u));
        const bool hi = (ia & 1u) != 0u;
        const float fa0 = hi ? blk.z : blk.x;
        const float fa1 = hi ? blk.w : blk.y;
        float fb0 = hi ? blk.x : blk.z;   // buddy entry = ia^1
        float fb1 = hi ? blk.y : blk.w;
        if (ib != (ia ^ 1u)) {            // buddy isn't corner_b: extra gather
            const float2 fb = *reinterpret_cast<const float2*>(tb + 2u * ib);
            fb0 = fb.x; fb1 = fb.y;
        }
        a0 = fmaf(fa0, wa, fmaf(fb0, wb, a0));
        a1 = fmaf(fa1, wa, fmaf(fb1, wb, a1));
    }

    float* dst = ws_enc + 2 * ((size_t)level * n + i);
    __builtin_nontemporal_store(a0, dst + 0);
    __builtin_nontemporal_store(a1, dst + 1);
}

// ---------------------------------------------------------------------------
// MFMA MLP, v2: 2-tile batching for 2x ILP per phase.
// Layouts (HW-verified, learn_hip m89/m91/m120):
//   A: m = lane&15, k = (lane>>4)*8 + j ;  B: n = lane&15, k = (lane>>4)*8 + j
//   D: col(n) = lane&15, row(m) = (lane>>4)*4 + reg
// sigma written straight from the accumulator (no LDS round-trip for col 0);
// geometry cols 1..16 stored bf16 at pitch 16 so an rgb-L1 A-frag is one
// 16 B ds_read. Weights staged once per block (transposed [n][k] bf16).
// ---------------------------------------------------------------------------
__global__ __launch_bounds__(256)
void mlp_mfma(const float* __restrict__ ws_enc,
              const float* __restrict__ dirv,
              const float* __restrict__ ws1,   // (32,64)
              const float* __restrict__ ws2,   // (64,17)
              const float* __restrict__ wr1,   // (32,64)
              const float* __restrict__ wr2,   // (64,64)
              const float* __restrict__ wr3,   // (64,3)
              float* __restrict__ out,
              int n)
{
    // LDS weight offsets (shorts):  ws1 @0 (64*40)  ws2 @2560 (32*72)
    // wr1 @4864 (64*40)  wr2 @7424 (64*72)  wr3 @12032 (16*72)  total 13184
    __shared__ alignas(16) unsigned short s_w[13184];
    __shared__ alignas(16) unsigned short s_act[4 * 2 * 16 * 72];  // [wave][tile][16][72]
    __shared__ alignas(16) unsigned short s_geo[4 * 2 * 16 * 16];  // [wave][tile][16][16] geo cols 1..16, bf16

    const int tid = threadIdx.x;

    for (int e = tid; e < 13184; e += 256) s_w[e] = 0;
    __syncthreads();
    for (int e = tid; e < 2048; e += 256) { const int k = e >> 6, j = e & 63; s_w[0     + j * 40 + k] = f2bf(ws1[e]); }
    for (int e = tid; e < 1088; e += 256) { const int k = e / 17, j = e % 17; s_w[2560  + j * 72 + k] = f2bf(ws2[e]); }
    for (int e = tid; e < 2048; e += 256) { const int k = e >> 6, j = e & 63; s_w[4864  + j * 40 + k] = f2bf(wr1[e]); }
    for (int e = tid; e < 4096; e += 256) { const int k = e >> 6, j = e & 63; s_w[7424  + j * 72 + k] = f2bf(wr2[e]); }
    for (int e = tid; e < 192;  e += 256) { const int k = e / 3,  j = e % 3;  s_w[12032 + j * 72 + k] = f2bf(wr3[e]); }
    __syncthreads();

    const int wave = tid >> 6;
    const int lane = tid & 63;
    const int q    = lane >> 4;    // quad 0..3
    const int mr   = lane & 15;    // row/col-within-16
    unsigned short* const hb0 = s_act + wave * (2 * 16 * 72);
    unsigned short* const gb0 = s_geo + wave * (2 * 16 * 16);
    const int base = blockIdx.x * 256 + wave * 64;

#pragma unroll 1
    for (int bt = 0; bt < 2; ++bt) {
        const int tb0 = base + bt * 32;     // two 16-point tiles: tb0, tb0+16

        // ---- phase 1: enc A-fragments for both tiles (global fp32 -> bf16)
        short8 aenc[2];
#pragma unroll
        for (int t = 0; t < 2; ++t) {
            const int pt = tb0 + t * 16 + mr;
#pragma unroll
            for (int tt = 0; tt < 4; ++tt) {
                const float2 e = *reinterpret_cast<const float2*>(
                    ws_enc + 2 * ((size_t)(q * 4 + tt) * n + pt));
                aenc[t][2 * tt + 0] = (short)f2bf(e.x);
                aenc[t][2 * tt + 1] = (short)f2bf(e.y);
            }
        }

        // ---- phase 2: sigma L1  enc(32) -> h(64), both tiles (8 indep MFMA)
#pragma unroll
        for (int t = 0; t < 2; ++t) {
            unsigned short* const hbt = hb0 + t * (16 * 72);
#pragma unroll
            for (int nc = 0; nc < 4; ++nc) {
                const short8 b = *reinterpret_cast<const short8*>(s_w + (nc * 16 + mr) * 40 + q * 8);
                floatx4 acc = {0.f, 0.f, 0.f, 0.f};
                acc = __builtin_amdgcn_mfma_f32_16x16x32_bf16(aenc[t], b, acc, 0, 0, 0);
#pragma unroll
                for (int r = 0; r < 4; ++r)
                    hbt[(q * 4 + r) * 72 + nc * 16 + mr] = f2bf(fmaxf(acc[r], 0.f));
            }
        }
        __builtin_amdgcn_wave_barrier();

        // ---- phase 3: sigma L2  h(64) -> geo(17 pad 32); sigma straight out
#pragma unroll
        for (int t = 0; t < 2; ++t) {
            unsigned short* const hbt = hb0 + t * (16 * 72);
            unsigned short* const gbt = gb0 + t * (16 * 16);
            const short8 a0 = *reinterpret_cast<const short8*>(hbt + mr * 72 + 0  + q * 8);
            const short8 a1 = *reinterpret_cast<const short8*>(hbt + mr * 72 + 32 + q * 8);
            const short8 b00 = *reinterpret_cast<const short8*>(s_w + 2560 + mr * 72 + 0  + q * 8);
            const short8 b01 = *reinterpret_cast<const short8*>(s_w + 2560 + mr * 72 + 32 + q * 8);
            const short8 b10 = *reinterpret_cast<const short8*>(s_w + 2560 + (16 + mr) * 72 + 0  + q * 8);
            const short8 b11 = *reinterpret_cast<const short8*>(s_w + 2560 + (16 + mr) * 72 + 32 + q * 8);
            floatx4 acc0 = {0.f, 0.f, 0.f, 0.f};
            floatx4 acc1 = {0.f, 0.f, 0.f, 0.f};
            acc0 = __builtin_amdgcn_mfma_f32_16x16x32_bf16(a0, b00, acc0, 0, 0, 0);
            acc0 = __builtin_amdgcn_mfma_f32_16x16x32_bf16(a1, b01, acc0, 0, 0, 0);
            acc1 = __builtin_amdgcn_mfma_f32_16x16x32_bf16(a0, b10, acc1, 0, 0, 0);
            acc1 = __builtin_amdgcn_mfma_f32_16x16x32_bf16(a1, b11, acc1, 0, 0, 0);
            if (mr == 0) {
#pragma unroll
                for (int r = 0; r < 4; ++r) {
                    out[3 * (size_t)n + (size_t)(tb0 + t * 16 + q * 4 + r)] = fmaxf(acc0[r], 0.f);
                    gbt[(q * 4 + r) * 16 + 15] = f2bf(acc1[r]);   // geometry col 16
                }
            } else {
#pragma unroll
                for (int r = 0; r < 4; ++r)
                    gbt[(q * 4 + r) * 16 + (mr - 1)] = f2bf(acc0[r]);  // geometry cols 1..15
            }
        }
        __builtin_amdgcn_wave_barrier();

        // ---- phase 4/5: SH + rgb L1  rin(32) -> g(64)  (g overwrites h)
#pragma unroll
        for (int t = 0; t < 2; ++t) {
            unsigned short* const hbt = hb0 + t * (16 * 72);
            unsigned short* const gbt = gb0 + t * (16 * 16);
            short8 ar;
            if (q < 2) {
                const int pt = tb0 + t * 16 + mr;
                const float dx = dirv[3 * (size_t)pt + 0] * 2.0f - 1.0f;
                const float dy = dirv[3 * (size_t)pt + 1] * 2.0f - 1.0f;
                const float dz = dirv[3 * (size_t)pt + 2] * 2.0f - 1.0f;
                const float x2 = dx * dx, y2 = dy * dy, z2 = dz * dz;
                const float xy = dx * dy, yz = dy * dz, xz = dx * dz;
                if (q == 0) {
                    ar[0] = (short)f2bf(0.28209479177387814f);
                    ar[1] = (short)f2bf(-0.48860251190291987f * dy);
                    ar[2] = (short)f2bf(0.48860251190291987f * dz);
                    ar[3] = (short)f2bf(-0.48860251190291987f * dx);
                    ar[4] = (short)f2bf(1.0925484305920792f * xy);
                    ar[5] = (short)f2bf(-1.0925484305920792f * yz);
                    ar[6] = (short)f2bf(0.94617469575756f * z2 - 0.31539156525252f);
                    ar[7] = (short)f2bf(-1.0925484305920792f * xz);
                } else {
                    ar[0] = (short)f2bf(0.5462742152960396f * (x2 - y2));
                    ar[1] = (short)f2bf(0.5900435899266435f * dy * (-3.0f * x2 + y2));
                    ar[2] = (short)f2bf(2.890611442640554f * xy * dz);
                    ar[3] = (short)f2bf(0.4570457994644657f * dy * (1.0f - 5.0f * z2));
                    ar[4] = (short)f2bf(0.3731763325901154f * dz * (5.0f * z2 - 3.0f));
                    ar[5] = (short)f2bf(0.4570457994644657f * dx * (1.0f - 5.0f * z2));
                    ar[6] = (short)f2bf(1.445305721320277f * dz * (x2 - y2));
                    ar[7] = (short)f2bf(0.5900435899266435f * dx * (-x2 + 3.0f * y2));
                }
            } else {
                ar = *reinterpret_cast<const short8*>(gbt + mr * 16 + (q - 2) * 8);
            }
#pragma unroll
            for (int nc = 0; nc < 4; ++nc) {
                const short8 b = *reinterpret_cast<const short8*>(s_w + 4864 + (nc * 16 + mr) * 40 + q * 8);
                floatx4 acc = {0.f, 0.f, 0.f, 0.f};
                acc = __builtin_amdgcn_mfma_f32_16x16x32_bf16(ar, b, acc, 0, 0, 0);
#pragma unroll
                for (int r = 0; r < 4; ++r)
                    hbt[(q * 4 + r) * 72 + nc * 16 + mr] = f2bf(fmaxf(acc[r], 0.f));
            }
        }
        __builtin_amdgcn_wave_barrier();

        // ---- phase 6: rgb L2  g(64) -> g2(64), in place (read frags first)
        short8 ga[2][2];
#pragma unroll
        for (int t = 0; t < 2; ++t) {
            unsigned short* const hbt = hb0 + t * (16 * 72);
            ga[t][0] = *reinterpret_cast<const short8*>(hbt + mr * 72 + 0  + q * 8);
            ga[t][1] = *reinterpret_cast<const short8*>(hbt + mr * 72 + 32 + q * 8);
        }
        __builtin_amdgcn_wave_barrier();
#pragma unroll
        for (int t = 0; t < 2; ++t) {
            unsigned short* const hbt = hb0 + t * (16 * 72);
#pragma unroll
            for (int nc = 0; nc < 4; ++nc) {
                const short8 b0 = *reinterpret_cast<const short8*>(s_w + 7424 + (nc * 16 + mr) * 72 + 0  + q * 8);
                const short8 b1 = *reinterpret_cast<const short8*>(s_w + 7424 + (nc * 16 + mr) * 72 + 32 + q * 8);
                floatx4 acc = {0.f, 0.f, 0.f, 0.f};
                acc = __builtin_amdgcn_mfma_f32_16x16x32_bf16(ga[t][0], b0, acc, 0, 0, 0);
                acc = __builtin_amdgcn_mfma_f32_16x16x32_bf16(ga[t][1], b1, acc, 0, 0, 0);
#pragma unroll
                for (int r = 0; r < 4; ++r)
                    hbt[(q * 4 + r) * 72 + nc * 16 + mr] = f2bf(fmaxf(acc[r], 0.f));
            }
        }
        __builtin_amdgcn_wave_barrier();

        // ---- phase 7: rgb L3  g2(64) -> rgb(3 pad 16), sigmoid, store
#pragma unroll
        for (int t = 0; t < 2; ++t) {
            unsigned short* const hbt = hb0 + t * (16 * 72);
            const short8 a0 = *reinterpret_cast<const short8*>(hbt + mr * 72 + 0  + q * 8);
            const short8 a1 = *reinterpret_cast<const short8*>(hbt + mr * 72 + 32 + q * 8);
            const short8 b0 = *reinterpret_cast<const short8*>(s_w + 12032 + mr * 72 + 0  + q * 8);
            const short8 b1 = *reinterpret_cast<const short8*>(s_w + 12032 + mr * 72 + 32 + q * 8);
            floatx4 acc = {0.f, 0.f, 0.f, 0.f};
            acc = __builtin_amdgcn_mfma_f32_16x16x32_bf16(a0, b0, acc, 0, 0, 0);
            acc = __builtin_amdgcn_mfma_f32_16x16x32_bf16(a1, b1, acc, 0, 0, 0);
            if (mr < 3) {
#pragma unroll
                for (int r = 0; r < 4; ++r) {
                    const int p = tb0 + t * 16 + q * 4 + r;
                    out[3 * (size_t)p + mr] = 1.0f / (1.0f + __expf(-acc[r]));
                }
            }
        }
        __builtin_amdgcn_wave_barrier();
    }
}

// ---------------------------------------------------------------------------
// Fallback: round-3 fused kernel (used only if ws can't hold enc or n%256).
// ---------------------------------------------------------------------------
__global__ __launch_bounds__(256, 4)
void nerf_fused(const float* __restrict__ xyz,
                const float* __restrict__ dirv,
                const float* __restrict__ table,
                const float* __restrict__ ws1,
                const float* __restrict__ ws2,
                const float* __restrict__ wr1,
                const float* __restrict__ wr2,
                const float* __restrict__ wr3,
                float* __restrict__ out,
                int n)
{
    constexpr unsigned RES[16] = RES_LIST;

    const int i = blockIdx.x * 256 + threadIdx.x;
    if (i >= n) return;

    const float px_ = xyz[3 * (size_t)i + 0];
    const float py_ = xyz[3 * (size_t)i + 1];
    const float pz_ = xyz[3 * (size_t)i + 2];

    float enc[32];
#pragma unroll
    for (int l = 0; l < 16; ++l) {
        const unsigned res = RES[l];
        const float fr = (float)res;
        const float posx = px_ * fr, posy = py_ * fr, posz = pz_ * fr;
        const float fx = floorf(posx), fy = floorf(posy), fz = floorf(posz);
        const float wx = posx - fx, wy = posy - fy, wz = posz - fz;
        const unsigned x0 = (unsigned)fx, y0 = (unsigned)fy, z0 = (unsigned)fz;
        const float* tb = table + (size_t)l * (TBL * 2);
        float a0 = 0.0f, a1 = 0.0f;
#pragma unroll
        for (int c = 0; c < 8; ++c) {
            const unsigned cx = x0 + (c & 1);
            const unsigned cy = y0 + ((c >> 1) & 1);
            const unsigned cz = z0 + ((c >> 2) & 1);
            unsigned idx;
            if (l < 5) {
                const unsigned s = res + 1u;
                idx = cx + cy * s + cz * (s * s);
            } else {
                idx = (cx * 1u) ^ (cy * 2654435761u) ^ (cz * 805459861u);
                idx &= (unsigned)(TBL - 1);
            }
            const float w = ((c & 1) ? wx : 1.0f - wx) *
                            ((c & 2) ? wy : 1.0f - wy) *
                            ((c & 4) ? wz : 1.0f - wz);
            const float2 f = *reinterpret_cast<const float2*>(tb + 2u * idx);
            a0 = fmaf(f.x, w, a0);
            a1 = fmaf(f.y, w, a1);
        }
        enc[2 * l + 0] = a0;
        enc[2 * l + 1] = a1;
    }

    float h[64];
#pragma unroll
    for (int j = 0; j < 64; ++j) h[j] = 0.0f;
#pragma unroll
    for (int k = 0; k < 32; ++k) {
        const float e = enc[k];
#pragma unroll
        for (int j = 0; j < 64; ++j) h[j] = fmaf(e, ws1[k * 64 + j], h[j]);
    }
#pragma unroll
    for (int j = 0; j < 64; ++j) h[j] = relu_f(h[j]);

    float geo[17];
#pragma unroll
    for (int j = 0; j < 17; ++j) geo[j] = 0.0f;
#pragma unroll
    for (int k = 0; k < 64; ++k) {
        const float e = h[k];
#pragma unroll
        for (int j = 0; j < 17; ++j) geo[j] = fmaf(e, ws2[k * 17 + j], geo[j]);
    }
    out[3 * (size_t)n + (size_t)i] = relu_f(geo[0]);

    const float dx = dirv[3 * (size_t)i + 0] * 2.0f - 1.0f;
    const float dy = dirv[3 * (size_t)i + 1] * 2.0f - 1.0f;
    const float dz = dirv[3 * (size_t)i + 2] * 2.0f - 1.0f;
    const float x2 = dx * dx, y2 = dy * dy, z2 = dz * dz;
    const float xy = dx * dy, yz = dy * dz, xz = dx * dz;

    float sh[16];
    sh[0]  = 0.28209479177387814f;
    sh[1]  = -0.48860251190291987f * dy;
    sh[2]  = 0.48860251190291987f * dz;
    sh[3]  = -0.48860251190291987f * dx;
    sh[4]  = 1.0925484305920792f * xy;
    sh[5]  = -1.0925484305920792f * yz;
    sh[6]  = 0.94617469575756f * z2 - 0.31539156525252f;
    sh[7]  = -1.0925484305920792f * xz;
    sh[8]  = 0.5462742152960396f * (x2 - y2);
    sh[9]  = 0.5900435899266435f * dy * (-3.0f * x2 + y2);
    sh[10] = 2.890611442640554f * xy * dz;
    sh[11] = 0.4570457994644657f * dy * (1.0f - 5.0f * z2);
    sh[12] = 0.3731763325901154f * dz * (5.0f * z2 - 3.0f);
    sh[13] = 0.4570457994644657f * dx * (1.0f - 5.0f * z2);
    sh[14] = 1.445305721320277f * dz * (x2 - y2);
    sh[15] = 0.5900435899266435f * dx * (-x2 + 3.0f * y2);

    float g[64];
#pragma unroll
    for (int j = 0; j < 64; ++j) g[j] = 0.0f;
#pragma unroll
    for (int k = 0; k < 16; ++k) {
        const float e = sh[k];
#pragma unroll
        for (int j = 0; j < 64; ++j) g[j] = fmaf(e, wr1[k * 64 + j], g[j]);
    }
#pragma unroll
    for (int k = 16; k < 32; ++k) {
        const float e = geo[k - 15];
#pragma unroll
        for (int j = 0; j < 64; ++j) g[j] = fmaf(e, wr1[k * 64 + j], g[j]);
    }
#pragma unroll
    for (int j = 0; j < 64; ++j) g[j] = relu_f(g[j]);

    float r0 = 0.0f, r1 = 0.0f, r2 = 0.0f;
#pragma unroll
    for (int half = 0; half < 2; ++half) {
        const int j0 = half * 32;
        float g2h[32];
#pragma unroll
        for (int j = 0; j < 32; ++j) g2h[j] = 0.0f;
#pragma unroll
        for (int k = 0; k < 64; ++k) {
            const float e = g[k];
#pragma unroll
            for (int j = 0; j < 32; ++j) g2h[j] = fmaf(e, wr2[k * 64 + j0 + j], g2h[j]);
        }
#pragma unroll
        for (int j = 0; j < 32; ++j) {
            const float e = relu_f(g2h[j]);
            r0 = fmaf(e, wr3[(j0 + j) * 3 + 0], r0);
            r1 = fmaf(e, wr3[(j0 + j) * 3 + 1], r1);
            r2 = fmaf(e, wr3[(j0 + j) * 3 + 2], r2);
        }
    }

    out[3 * (size_t)i + 0] = 1.0f / (1.0f + __expf(-r0));
    out[3 * (size_t)i + 1] = 1.0f / (1.0f + __expf(-r1));
    out[3 * (size_t)i + 2] = 1.0f / (1.0f + __expf(-r2));
}

extern "C" void kernel_launch(void* const* d_in, const int* in_sizes, int n_in,
                              void* d_out, int out_size, void* d_ws, size_t ws_size,
                              hipStream_t stream)
{
    const float* xyz   = (const float*)d_in[0];
    const float* dirv  = (const float*)d_in[1];
    const float* table = (const float*)d_in[2];
    const float* ws1   = (const float*)d_in[3];
    const float* ws2   = (const float*)d_in[4];
    const float* wr1   = (const float*)d_in[5];
    const float* wr2   = (const float*)d_in[6];
    const float* wr3   = (const float*)d_in[7];
    float* out = (float*)d_out;

    const int n = in_sizes[0] / 3;
    const int blocks_per_level = (n + 255) / 256;
    dim3 block(256);
    dim3 grid_mlp(blocks_per_level);
    dim3 grid_enc(8 * blocks_per_level);

    const size_t enc_bytes = (size_t)n * 16 * sizeof(float2);   // 268 MB at n=2^21
    if (ws_size >= enc_bytes && (n & 255) == 0) {
        float* ws_enc = (float*)d_ws;
        // pass A: hashed levels 5..12, one per XCD (4 MB table == 4 MB L2)
        hipLaunchKernelGGL(encode_pinned, grid_enc, block, 0, stream,
                           xyz, table, ws_enc, 0xCBA98765u, n);
        // pass B: levels 13,14,15 on XCDs 0..2; dense 0..4 on XCDs 3..7
        hipLaunchKernelGGL(encode_pinned, grid_enc, block, 0, stream,
                           xyz, table, ws_enc, 0x43210FEDu, n);
        hipLaunchKernelGGL(mlp_mfma, grid_mlp, block, 0, stream,
                           ws_enc, dirv, ws1, ws2, wr1, wr2, wr3, out, n);
    } else {
        hipLaunchKernelGGL(nerf_fused, grid_mlp, block, 0, stream,
                           xyz, dirv, table, ws1, ws2, wr1, wr2, wr3, out, n);
    }
}